// Round 7
// baseline (274.769 us; speedup 1.0000x reference)
//
#include <hip/hip_runtime.h>
#include <stdint.h>

#define B_  4
#define S_  2048
#define DM_ 1024
#define NH_ 16
#define HD_ 64

typedef unsigned short ushort_t;
typedef __bf16 bf16x8 __attribute__((ext_vector_type(8)));
typedef float  floatx4 __attribute__((ext_vector_type(4)));
typedef float  floatx16 __attribute__((ext_vector_type(16)));

__device__ __forceinline__ float bf2f(ushort_t u) {
    union { unsigned int i; float f; } v; v.i = ((unsigned int)u) << 16; return v.f;
}
__device__ __forceinline__ ushort_t f2bf(float f) {
    union { float f; unsigned int i; } v; v.f = f;
    unsigned int x = v.i;
    return (ushort_t)((x + 0x7fffu + ((x >> 16) & 1u)) >> 16);
}
__device__ __forceinline__ unsigned int pack_bf16_trunc(float lo, float hi) {
    union { float f; unsigned int u; } a, b;
    a.f = lo; b.f = hi;
    return __builtin_amdgcn_perm(b.u, a.u, 0x07060302u);
}

#define QSCALE 0.1803368801f   // 0.125 * log2(e)

// ---------------------------------------------------------------------------
// fused f32 -> bf16 conversion: x (8192 blocks) + 4 weights (1024 each)
// ---------------------------------------------------------------------------
__global__ __launch_bounds__(256) void cvt_all_kernel(
    const float* __restrict__ x,  const float* __restrict__ wq,
    const float* __restrict__ wk, const float* __restrict__ wv,
    const float* __restrict__ wo,
    ushort_t* __restrict__ xb,  ushort_t* __restrict__ wqb,
    ushort_t* __restrict__ wkb, ushort_t* __restrict__ wvb,
    ushort_t* __restrict__ wob)
{
    const int blk = blockIdx.x;
    const float* src; ushort_t* dst; int off;
    if (blk < 8192)       { src = x;  dst = xb;  off = blk; }
    else if (blk < 9216)  { src = wq; dst = wqb; off = blk - 8192; }
    else if (blk < 10240) { src = wk; dst = wkb; off = blk - 9216; }
    else if (blk < 11264) { src = wv; dst = wvb; off = blk - 10240; }
    else                  { src = wo; dst = wob; off = blk - 11264; }
    const int i = off * 256 + threadIdx.x;
    float4 v = ((const float4*)src)[i];
    ushort4 o; o.x = f2bf(v.x); o.y = f2bf(v.y); o.z = f2bf(v.z); o.w = f2bf(v.w);
    ((ushort4*)dst)[i] = o;
}

// ---------------------------------------------------------------------------
// QKV GEMM: C = A @ B^T — 256x128 tile, BK=64, FOUR waves of 128x64 each
// (wave grid 2x2: wr->128 rows, wc->64 cols). Per-wave arithmetic intensity
// 42.7 FLOP/LDS-byte (vs 32 for 64x64 waves) — the m201 ratio. 2 phases per
// K-tile, 32-MFMA clusters, 4 barriers/tile. LDS 96 KB (1 block/CU, 3
// rounds). Chunk-XOR swizzle; counted vmcnt(4).
// Ph1: read A mt0-3 + B all; stage A(t+1)->buf^1 (A[buf^1] dead since t-1).
// Ph2: read A mt4-7; stage B(t+2)->cur buf (B[cur] reads drained at Ph1
// lgkmcnt(0), all waves past Ph1 barrier). Boundary vmcnt(4) keeps B(t+2).
// RoPE fused into Q/K epilogue; z=2 writes V^T (B,H,64,S).
// ---------------------------------------------------------------------------
__global__ __launch_bounds__(256, 1) void gemm_qkv_kernel(
    const ushort_t* __restrict__ A,
    const ushort_t* __restrict__ B0, const ushort_t* __restrict__ B1,
    const ushort_t* __restrict__ B2,
    void* __restrict__ C0, void* __restrict__ C1, void* __restrict__ C2,
    const float* __restrict__ cf, const float* __restrict__ sf,
    int M, int N, int K, int nz)
{
    __shared__ ushort_t As[2][16384];   // 256 rows x 64, chunk-swizzled
    __shared__ ushort_t Bs[2][8192];    // 128 rows x 64, chunk-swizzled

    const int lid = blockIdx.x;
    const int cpx = gridDim.x >> 3;
    const int wg  = (lid & 7) * cpx + (lid >> 3);
    const int x   = wg / (8 * nz);
    const int rr  = wg - x * (8 * nz);
    const int y   = rr & 7;
    const int z   = rr >> 3;

    const ushort_t* Bw = z == 0 ? B0 : z == 1 ? B1 : B2;
    void* Cv           = z == 0 ? C0 : z == 1 ? C1 : C2;

    const int tid  = threadIdx.x;
    const int wave = tid >> 6, lane = tid & 63;
    const int l15 = lane & 15, quad = lane >> 4;
    const int wr = wave >> 1, wc = wave & 1;   // 2 x 2 wave grid
    const int mbase = x * 256;
    const int nbase = y * 128;
    const int NT = K >> 6;

    auto stageA = [&](int bt, int t) {
#pragma unroll
        for (int L = 0; L < 8; ++L) {
            const int e8  = L * 256 + tid;
            const int row = e8 >> 3, c = e8 & 7;
            const ushort_t* src = A + (size_t)(mbase + row) * K + t * 64 + ((c ^ (row & 7)) << 3);
            __builtin_amdgcn_global_load_lds(
                (const __attribute__((address_space(1))) unsigned int*)src,
                (__attribute__((address_space(3))) unsigned int*)(&As[bt][e8 * 8]), 16, 0, 0);
        }
    };
    auto stageB = [&](int bt, int t) {
#pragma unroll
        for (int L = 0; L < 4; ++L) {
            const int e8  = L * 256 + tid;
            const int row = e8 >> 3, c = e8 & 7;
            const ushort_t* src = Bw + (size_t)(nbase + row) * K + t * 64 + ((c ^ (row & 7)) << 3);
            __builtin_amdgcn_global_load_lds(
                (const __attribute__((address_space(1))) unsigned int*)src,
                (__attribute__((address_space(3))) unsigned int*)(&Bs[bt][e8 * 8]), 16, 0, 0);
        }
    };

    floatx4 acc[8][4] = {};

    // prologue: A0,B0 -> buf0; B1 -> buf1 (stays in flight past the wait)
    stageA(0, 0);
    stageB(0, 0);
    if (NT > 1) {
        stageB(1, 1);
        asm volatile("s_waitcnt vmcnt(4)" ::: "memory");
    } else {
        asm volatile("s_waitcnt vmcnt(0)" ::: "memory");
    }
    __builtin_amdgcn_s_barrier();

    for (int t = 0; t < NT; ++t) {
        const int bt = t & 1;
        bf16x8 a0[2][4], a1[2][4], bf[2][4];

        // ---- Ph1: read A mt0-3 + B all ; stage A(t+1)->buf^1 ;
        //           MFMA acc[0..3][*] (32 MFMA) ----
#pragma unroll
        for (int kk = 0; kk < 2; ++kk) {
#pragma unroll
            for (int f = 0; f < 4; ++f) {
                const int row = wr * 128 + f * 16 + l15;
                a0[kk][f] = *(const bf16x8*)&As[bt][row * 64 + ((((kk << 2) | quad)) ^ (l15 & 7)) * 8];
            }
#pragma unroll
            for (int g = 0; g < 4; ++g) {
                const int row = wc * 64 + g * 16 + l15;
                bf[kk][g] = *(const bf16x8*)&Bs[bt][row * 64 + ((((kk << 2) | quad)) ^ (l15 & 7)) * 8];
            }
        }
        if (t + 1 < NT) stageA(bt ^ 1, t + 1);
        __builtin_amdgcn_s_barrier();
        asm volatile("s_waitcnt lgkmcnt(0)" ::: "memory");
        __builtin_amdgcn_s_setprio(1);
#pragma unroll
        for (int kk = 0; kk < 2; ++kk)
#pragma unroll
            for (int mt = 0; mt < 4; ++mt)
#pragma unroll
                for (int nt = 0; nt < 4; ++nt)
                    acc[mt][nt] = __builtin_amdgcn_mfma_f32_16x16x32_bf16(
                        a0[kk][mt], bf[kk][nt], acc[mt][nt], 0, 0, 0);
        __builtin_amdgcn_s_setprio(0);
        __builtin_amdgcn_s_barrier();

        // ---- Ph2: read A mt4-7 ; stage B(t+2)->cur buf ;
        //           MFMA acc[4..7][*] (32 MFMA) ; counted vmcnt ----
#pragma unroll
        for (int kk = 0; kk < 2; ++kk)
#pragma unroll
            for (int f = 0; f < 4; ++f) {
                const int row = wr * 128 + 64 + f * 16 + l15;
                a1[kk][f] = *(const bf16x8*)&As[bt][row * 64 + ((((kk << 2) | quad)) ^ (l15 & 7)) * 8];
            }
        if (t + 2 < NT) stageB(bt, t + 2);
        __builtin_amdgcn_s_barrier();
        asm volatile("s_waitcnt lgkmcnt(0)" ::: "memory");
        __builtin_amdgcn_s_setprio(1);
#pragma unroll
        for (int kk = 0; kk < 2; ++kk)
#pragma unroll
            for (int mt = 0; mt < 4; ++mt)
#pragma unroll
                for (int nt = 0; nt < 4; ++nt)
                    acc[4 + mt][nt] = __builtin_amdgcn_mfma_f32_16x16x32_bf16(
                        a1[kk][mt], bf[kk][nt], acc[4 + mt][nt], 0, 0, 0);
        __builtin_amdgcn_s_setprio(0);
        if (t + 2 < NT) { asm volatile("s_waitcnt vmcnt(4)" ::: "memory"); }
        else            { asm volatile("s_waitcnt vmcnt(0)" ::: "memory"); }
        __builtin_amdgcn_s_barrier();
    }

    const float qs = (z == 0) ? QSCALE : 1.0f;
#pragma unroll
    for (int mt = 0; mt < 8; ++mt) {
#pragma unroll
        for (int nt = 0; nt < 4; ++nt) {
            const int col = nbase + wc * 64 + nt * 16 + l15;
            const int m0  = mbase + wr * 128 + mt * 16 + quad * 4;
            if (z == 2) {
                const int b = m0 >> 11, s = m0 & 2047;
                const int hh = col >> 6, d = col & 63;
                uint2 pk;
                pk.x = (unsigned)f2bf(acc[mt][nt][0]) | ((unsigned)f2bf(acc[mt][nt][1]) << 16);
                pk.y = (unsigned)f2bf(acc[mt][nt][2]) | ((unsigned)f2bf(acc[mt][nt][3]) << 16);
                *(uint2*)&((ushort_t*)Cv)[((size_t)((b * NH_ + hh) * HD_ + d)) * S_ + s] = pk;
            } else {
                // fused RoPE: partner value lives in lane l15^1 (d^1)
                const int d = col & 63, j = d >> 1;
                const int hh = col >> 6;
                const float sgn = (l15 & 1) ? 1.0f : -1.0f;
#pragma unroll
                for (int r = 0; r < 4; ++r) {
                    const int m = m0 + r;
                    const int b = m >> 11, s = m & 2047;
                    const float v = acc[mt][nt][r];
                    const float p = __shfl_xor(v, 1, 64);
                    const float c  = cf[s * 32 + j] * qs;
                    const float sn = sf[s * 32 + j] * qs * sgn;
                    ((ushort_t*)Cv)[(((size_t)(b * NH_ + hh)) * S_ + s) * HD_ + d] =
                        f2bf(v * c + p * sn);
                }
            }
        }
    }
}

// ---------------------------------------------------------------------------
// Projection GEMM: C = A @ B^T — 128x128 tile, BK=64, 4 waves (2x2),
// 2 phases, 64 KB LDS -> 2 blocks/CU resident. f32 row-major output.
// Grid 1D = 64 * 8 = 512 blocks = 2/CU; XCD-aware decode. (unchanged)
// ---------------------------------------------------------------------------
__global__ __launch_bounds__(256, 2) void gemm_proj_kernel(
    const ushort_t* __restrict__ A, const ushort_t* __restrict__ Bw,
    float* __restrict__ Cv, int M, int N, int K)
{
    __shared__ ushort_t As[2][8192];    // 128 rows x 64, chunk-swizzled
    __shared__ ushort_t Bs[2][8192];

    const int lid = blockIdx.x;
    const int cpx = gridDim.x >> 3;
    const int wg  = (lid & 7) * cpx + (lid >> 3);
    const int x   = wg >> 3;
    const int y   = wg & 7;

    const int tid  = threadIdx.x;
    const int wave = tid >> 6, lane = tid & 63;
    const int l15 = lane & 15, quad = lane >> 4;
    const int wr = wave >> 1, wc = wave & 1;   // 2 x 2 wave grid
    const int mbase = x * 128;
    const int nbase = y * 128;
    const int NT = K >> 6;

    auto stageA = [&](int bt, int t) {
#pragma unroll
        for (int L = 0; L < 4; ++L) {
            const int e   = L * 256 + tid;
            const int row = e >> 3, c = e & 7;
            const ushort_t* src = A + (size_t)(mbase + row) * K + t * 64 + ((c ^ (row & 7)) << 3);
            __builtin_amdgcn_global_load_lds(
                (const __attribute__((address_space(1))) unsigned int*)src,
                (__attribute__((address_space(3))) unsigned int*)(&As[bt][e * 8]), 16, 0, 0);
        }
    };
    auto stageB = [&](int bt, int t) {
#pragma unroll
        for (int L = 0; L < 4; ++L) {
            const int e   = L * 256 + tid;
            const int row = e >> 3, c = e & 7;
            const ushort_t* src = Bw + (size_t)(nbase + row) * K + t * 64 + ((c ^ (row & 7)) << 3);
            __builtin_amdgcn_global_load_lds(
                (const __attribute__((address_space(1))) unsigned int*)src,
                (__attribute__((address_space(3))) unsigned int*)(&Bs[bt][e * 8]), 16, 0, 0);
        }
    };

    floatx4 acc[4][4] = {};

    stageA(0, 0);
    stageB(0, 0);
    if (NT > 1) {
        stageB(1, 1);
        asm volatile("s_waitcnt vmcnt(4)" ::: "memory");
    } else {
        asm volatile("s_waitcnt vmcnt(0)" ::: "memory");
    }
    __builtin_amdgcn_s_barrier();

    for (int t = 0; t < NT; ++t) {
        const int bt = t & 1;
        bf16x8 a0[2][2], a1[2][2], bf[2][4];

#pragma unroll
        for (int kk = 0; kk < 2; ++kk) {
#pragma unroll
            for (int f = 0; f < 2; ++f) {
                const int row = wr * 64 + f * 16 + l15;
                a0[kk][f] = *(const bf16x8*)&As[bt][row * 64 + ((((kk << 2) | quad)) ^ (l15 & 7)) * 8];
            }
#pragma unroll
            for (int g = 0; g < 4; ++g) {
                const int row = wc * 64 + g * 16 + l15;
                bf[kk][g] = *(const bf16x8*)&Bs[bt][row * 64 + ((((kk << 2) | quad)) ^ (l15 & 7)) * 8];
            }
        }
        if (t + 1 < NT) stageA(bt ^ 1, t + 1);
        asm volatile("s_waitcnt lgkmcnt(8)" ::: "memory");
        __builtin_amdgcn_s_barrier();
        asm volatile("s_waitcnt lgkmcnt(0)" ::: "memory");
        __builtin_amdgcn_s_setprio(1);
#pragma unroll
        for (int kk = 0; kk < 2; ++kk)
#pragma unroll
            for (int mt = 0; mt < 2; ++mt)
#pragma unroll
                for (int nt = 0; nt < 4; ++nt)
                    acc[mt][nt] = __builtin_amdgcn_mfma_f32_16x16x32_bf16(
                        a0[kk][mt], bf[kk][nt], acc[mt][nt], 0, 0, 0);
        __builtin_amdgcn_s_setprio(0);
        __builtin_amdgcn_s_barrier();

#pragma unroll
        for (int kk = 0; kk < 2; ++kk)
#pragma unroll
            for (int f = 0; f < 2; ++f) {
                const int row = wr * 64 + 32 + f * 16 + l15;
                a1[kk][f] = *(const bf16x8*)&As[bt][row * 64 + ((((kk << 2) | quad)) ^ (l15 & 7)) * 8];
            }
        if (t + 2 < NT) stageB(bt, t + 2);
        __builtin_amdgcn_s_barrier();
        asm volatile("s_waitcnt lgkmcnt(0)" ::: "memory");
        __builtin_amdgcn_s_setprio(1);
#pragma unroll
        for (int kk = 0; kk < 2; ++kk)
#pragma unroll
            for (int mt = 0; mt < 2; ++mt)
#pragma unroll
                for (int nt = 0; nt < 4; ++nt)
                    acc[2 + mt][nt] = __builtin_amdgcn_mfma_f32_16x16x32_bf16(
                        a1[kk][mt], bf[kk][nt], acc[2 + mt][nt], 0, 0, 0);
        __builtin_amdgcn_s_setprio(0);
        if (t + 2 < NT) { asm volatile("s_waitcnt vmcnt(4)" ::: "memory"); }
        else            { asm volatile("s_waitcnt vmcnt(0)" ::: "memory"); }
        __builtin_amdgcn_s_barrier();
    }

#pragma unroll
    for (int mt = 0; mt < 4; ++mt) {
#pragma unroll
        for (int nt = 0; nt < 4; ++nt) {
            const int col = nbase + wc * 64 + nt * 16 + l15;
            const int m0  = mbase + wr * 64 + mt * 16 + quad * 4;
#pragma unroll
            for (int r = 0; r < 4; ++r)
                Cv[(size_t)(m0 + r) * N + col] = acc[mt][nt][r];
        }
    }
}

// ---------------------------------------------------------------------------
// Causal flash attention v5: v4 + CU-level load-balance table.
// slot = id>>6 -> qtile via table: CU-groups {t,t+4,t+8,t+12} each sum to
// 68 tile-units (was 56..80). Heavy qtiles dispatched first within group.
// XCD/bh grouping unchanged (id&7 -> XCD, 8 bh per XCD = 4 MB L2-resident).
// ---------------------------------------------------------------------------
__global__ __launch_bounds__(256, 4) void attn_kernel(
    const ushort_t* __restrict__ Qg, const ushort_t* __restrict__ Kg,
    const ushort_t* __restrict__ Vg, ushort_t* __restrict__ Og)
{
    __shared__ ushort_t Ks[2][64 * 64];    // [key][dim-chunk ^ (key&7)]
    __shared__ ushort_t Vt[2][64 * 64];    // [dim][key-chunk ^ (dim&7)]

    const int qt_tab[16] = {15,13,11,9, 0,2,4,6, 14,12,10,8, 1,3,5,7};

    const int id   = blockIdx.x;
    const int sg   = id >> 3;
    const int bh   = (id & 7) * 8 + (sg & 7);
    const int qtile = qt_tab[sg >> 3];
    const int tid  = threadIdx.x;
    const int wave = tid >> 6, lane = tid & 63;
    const int l31 = lane & 31, h = lane >> 5;

    const size_t bh_off = (size_t)bh * S_ * HD_;
    const int b_out = bh >> 4, h_out = bh & 15;

    const int e0 = tid, e1 = tid + 256;
    const int r0 = e0 >> 3, c0 = (e0 & 7) ^ (r0 & 7);
    const int r1 = e1 >> 3, c1 = (e1 & 7) ^ (r1 & 7);

    const int qbase = qtile * 128;
    const int nkt   = 2 * qtile + 2;
    const int qrow  = qbase + wave * 32 + l31;

    bf16x8 qf[4];
#pragma unroll
    for (int ks = 0; ks < 4; ++ks)
        qf[ks] = *(const bf16x8*)(Qg + bh_off + (size_t)qrow * HD_ + ks * 16 + h * 8);

    float m_run = -1e30f, l_run = 0.f;
    floatx16 o_acc[2] = {};

    {
        const ushort_t* ka = Kg + bh_off + (size_t)r0 * HD_ + c0 * 8;
        const ushort_t* kb = Kg + bh_off + (size_t)r1 * HD_ + c1 * 8;
        const ushort_t* va = Vg + bh_off + (size_t)r0 * S_ + c0 * 8;
        const ushort_t* vb = Vg + bh_off + (size_t)r1 * S_ + c1 * 8;
        __builtin_amdgcn_global_load_lds(
            (const __attribute__((address_space(1))) unsigned int*)ka,
            (__attribute__((address_space(3))) unsigned int*)(&Ks[0][e0 * 8]), 16, 0, 0);
        __builtin_amdgcn_global_load_lds(
            (const __attribute__((address_space(1))) unsigned int*)kb,
            (__attribute__((address_space(3))) unsigned int*)(&Ks[0][e1 * 8]), 16, 0, 0);
        __builtin_amdgcn_global_load_lds(
            (const __attribute__((address_space(1))) unsigned int*)va,
            (__attribute__((address_space(3))) unsigned int*)(&Vt[0][e0 * 8]), 16, 0, 0);
        __builtin_amdgcn_global_load_lds(
            (const __attribute__((address_space(1))) unsigned int*)vb,
            (__attribute__((address_space(3))) unsigned int*)(&Vt[0][e1 * 8]), 16, 0, 0);
    }
    asm volatile("s_waitcnt vmcnt(0)" ::: "memory");
    __syncthreads();

    for (int kt = 0; kt < nkt; ++kt) {
        const int kbase = kt * 64;
        const int cur = kt & 1;

        if (kt + 1 < nkt) {
            const int nb = kbase + 64;
            const ushort_t* ka = Kg + bh_off + (size_t)(nb + r0) * HD_ + c0 * 8;
            const ushort_t* kb = Kg + bh_off + (size_t)(nb + r1) * HD_ + c1 * 8;
            const ushort_t* va = Vg + bh_off + (size_t)r0 * S_ + nb + c0 * 8;
            const ushort_t* vb = Vg + bh_off + (size_t)r1 * S_ + nb + c1 * 8;
            __builtin_amdgcn_global_load_lds(
                (const __attribute__((address_space(1))) unsigned int*)ka,
                (__attribute__((address_space(3))) unsigned int*)(&Ks[cur ^ 1][e0 * 8]), 16, 0, 0);
            __builtin_amdgcn_global_load_lds(
                (const __attribute__((address_space(1))) unsigned int*)kb,
                (__attribute__((address_space(3))) unsigned int*)(&Ks[cur ^ 1][e1 * 8]), 16, 0, 0);
            __builtin_amdgcn_global_load_lds(
                (const __attribute__((address_space(1))) unsigned int*)va,
                (__attribute__((address_space(3))) unsigned int*)(&Vt[cur ^ 1][e0 * 8]), 16, 0, 0);
            __builtin_amdgcn_global_load_lds(
                (const __attribute__((address_space(1))) unsigned int*)vb,
                (__attribute__((address_space(3))) unsigned int*)(&Vt[cur ^ 1][e1 * 8]), 16, 0, 0);
        }

        if (kbase <= qbase + wave * 32 + 31) {
            floatx16 st[2] = {};
#pragma unroll
            for (int nt = 0; nt < 2; ++nt) {
                const int krow = nt * 32 + l31;
#pragma unroll
                for (int ks = 0; ks < 4; ++ks) {
                    bf16x8 kf = *(const bf16x8*)&Ks[cur][krow * 64 +
                                    (((ks * 2 + h) ^ (l31 & 7)) << 3)];
                    st[nt] = __builtin_amdgcn_mfma_f32_32x32x16_bf16(kf, qf[ks], st[nt], 0, 0, 0);
                }
            }
            if (kbase + 63 > qbase + wave * 32) {
#pragma unroll
                for (int nt = 0; nt < 2; ++nt) {
                    const int key0 = kbase + nt * 32 + 4 * h;
#pragma unroll
                    for (int c = 0; c < 4; ++c)
#pragma unroll
                        for (int r = 0; r < 4; ++r)
                            if (key0 + 8 * c + r > qrow) st[nt][c * 4 + r] = -1e9f;
                }
            }
            float mx = st[0][0];
#pragma unroll
            for (int nt = 0; nt < 2; ++nt)
#pragma unroll
                for (int i = 0; i < 16; ++i) mx = fmaxf(mx, st[nt][i]);
            mx = fmaxf(mx, __shfl_xor(mx, 32, 64));
            if (!__all(mx <= m_run + 8.0f)) {
                const float mnew = fmaxf(m_run, mx);
                const float alpha = __builtin_amdgcn_exp2f(m_run - mnew);
                m_run = mnew;
                l_run *= alpha;
#pragma unroll
                for (int dt = 0; dt < 2; ++dt)
#pragma unroll
                    for (int i = 0; i < 16; ++i) o_acc[dt][i] *= alpha;
            }
            float sum = 0.f;
#pragma unroll
            for (int nt = 0; nt < 2; ++nt)
#pragma unroll
                for (int i = 0; i < 16; ++i) {
                    const float p = __builtin_amdgcn_exp2f(st[nt][i] - m_run);
                    st[nt][i] = p; sum += p;
                }
            sum += __shfl_xor(sum, 32, 64);
            l_run += sum;

            bf16x8 pf[4];
#pragma unroll
            for (int ks = 0; ks < 4; ++ks) {
                const int nt = ks >> 1, base = (ks & 1) * 8;
                unsigned wrd[4];
#pragma unroll
                for (int d8 = 0; d8 < 2; ++d8) {
                    unsigned p = pack_bf16_trunc(st[nt][base + 2 * d8],
                                                 st[nt][base + 2 * d8 + 1]);
                    unsigned q = pack_bf16_trunc(st[nt][base + 4 + 2 * d8],
                                                 st[nt][base + 4 + 2 * d8 + 1]);
                    auto r = __builtin_amdgcn_permlane32_swap((int)p, (int)q, false, false);
                    wrd[d8]     = (unsigned)r[0];
                    wrd[2 + d8] = (unsigned)r[1];
                }
                union { unsigned u[4]; bf16x8 v; } cvt;
                cvt.u[0] = wrd[0]; cvt.u[1] = wrd[1];
                cvt.u[2] = wrd[2]; cvt.u[3] = wrd[3];
                pf[ks] = cvt.v;
            }

#pragma unroll
            for (int dt = 0; dt < 2; ++dt) {
                const int d = dt * 32 + l31;
#pragma unroll
                for (int ks = 0; ks < 4; ++ks) {
                    bf16x8 vf = *(const bf16x8*)&Vt[cur][d * 64 +
                                    (((ks * 2 + h) ^ (l31 & 7)) << 3)];
                    o_acc[dt] = __builtin_amdgcn_mfma_f32_32x32x16_bf16(vf, pf[ks], o_acc[dt], 0, 0, 0);
                }
            }
        }

        asm volatile("s_waitcnt vmcnt(0)" ::: "memory");
        __syncthreads();
    }

    const float inv = 1.0f / l_run;
    ushort_t* orow = Og + ((size_t)(b_out * S_ + qrow)) * DM_ + h_out * HD_;
#pragma unroll
    for (int dt = 0; dt < 2; ++dt)
#pragma unroll
        for (int c = 0; c < 4; ++c) {
            uint2 pk;
            pk.x = (unsigned)f2bf(o_acc[dt][c * 4 + 0] * inv) |
                   ((unsigned)f2bf(o_acc[dt][c * 4 + 1] * inv) << 16);
            pk.y = (unsigned)f2bf(o_acc[dt][c * 4 + 2] * inv) |
                   ((unsigned)f2bf(o_acc[dt][c * 4 + 3] * inv) << 16);
            *(uint2*)(orow + dt * 32 + 8 * c + 4 * h) = pk;
        }
}

// ---------------------------------------------------------------------------
extern "C" void kernel_launch(void* const* d_in, const int* in_sizes, int n_in,
                              void* d_out, int out_size, void* d_ws, size_t ws_size,
                              hipStream_t stream)
{
    const float* x  = (const float*)d_in[0];
    const float* cf = (const float*)d_in[1];
    const float* sf = (const float*)d_in[2];
    // d_in[3] = causal_mask: computed analytically, never read
    const float* wq = (const float*)d_in[4];
    const float* wk = (const float*)d_in[5];
    const float* wv = (const float*)d_in[6];
    const float* wo = (const float*)d_in[7];
    float* out = (float*)d_out;

    const size_t NELEM = (size_t)B_ * S_ * DM_;   // 8388608
    const size_t WELEM = (size_t)DM_ * DM_;       // 1048576
    ushort_t* xb  = (ushort_t*)d_ws;
    ushort_t* qb  = xb + NELEM;
    ushort_t* kb  = qb + NELEM;
    ushort_t* vb  = kb + NELEM;                   // V^T (B,H,64,S)
    ushort_t* ao  = vb + NELEM;
    ushort_t* wqb = ao + NELEM;
    ushort_t* wkb = wqb + WELEM;
    ushort_t* wvb = wkb + WELEM;
    ushort_t* wob = wvb + WELEM;

    cvt_all_kernel<<<dim3(8192 + 4 * 1024), 256, 0, stream>>>(
        x, wq, wk, wv, wo, xb, wqb, wkb, wvb, wob);

    const int M = B_ * S_;
    // QKV (+fused RoPE): 32 * 8 * 3 = 768 blocks = exactly 3/CU, 256 thr
    gemm_qkv_kernel<<<dim3(32 * 8 * 3), 256, 0, stream>>>(
        xb, wqb, wkb, wvb, qb, kb, vb, cf, sf, M, DM_, DM_, 3);
    attn_kernel<<<dim3(1024), 256, 0, stream>>>(qb, kb, vb, ao);
    // proj: 64 * 8 = 512 blocks = 2/CU resident
    gemm_proj_kernel<<<dim3(64 * 8), 256, 0, stream>>>(
        ao, wob, out, M, DM_, DM_);
}

// Round 8
// 251.636 us; speedup vs baseline: 1.0919x; 1.0919x over previous
//
#include <hip/hip_runtime.h>
#include <stdint.h>

#define B_  4
#define S_  2048
#define DM_ 1024
#define NH_ 16
#define HD_ 64

typedef unsigned short ushort_t;
typedef __bf16 bf16x8 __attribute__((ext_vector_type(8)));
typedef float  floatx4 __attribute__((ext_vector_type(4)));
typedef float  floatx16 __attribute__((ext_vector_type(16)));

__device__ __forceinline__ float bf2f(ushort_t u) {
    union { unsigned int i; float f; } v; v.i = ((unsigned int)u) << 16; return v.f;
}
__device__ __forceinline__ ushort_t f2bf(float f) {
    union { float f; unsigned int i; } v; v.f = f;
    unsigned int x = v.i;
    return (ushort_t)((x + 0x7fffu + ((x >> 16) & 1u)) >> 16);
}
__device__ __forceinline__ unsigned int pack_bf16_trunc(float lo, float hi) {
    union { float f; unsigned int u; } a, b;
    a.f = lo; b.f = hi;
    return __builtin_amdgcn_perm(b.u, a.u, 0x07060302u);
}

#define QSCALE 0.1803368801f   // 0.125 * log2(e)

// ---------------------------------------------------------------------------
// fused f32 -> bf16 conversion: x (8192 blocks) + 4 weights (1024 each)
// ---------------------------------------------------------------------------
__global__ __launch_bounds__(256) void cvt_all_kernel(
    const float* __restrict__ x,  const float* __restrict__ wq,
    const float* __restrict__ wk, const float* __restrict__ wv,
    const float* __restrict__ wo,
    ushort_t* __restrict__ xb,  ushort_t* __restrict__ wqb,
    ushort_t* __restrict__ wkb, ushort_t* __restrict__ wvb,
    ushort_t* __restrict__ wob)
{
    const int blk = blockIdx.x;
    const float* src; ushort_t* dst; int off;
    if (blk < 8192)       { src = x;  dst = xb;  off = blk; }
    else if (blk < 9216)  { src = wq; dst = wqb; off = blk - 8192; }
    else if (blk < 10240) { src = wk; dst = wkb; off = blk - 9216; }
    else if (blk < 11264) { src = wv; dst = wvb; off = blk - 10240; }
    else                  { src = wo; dst = wob; off = blk - 11264; }
    const int i = off * 256 + threadIdx.x;
    float4 v = ((const float4*)src)[i];
    ushort4 o; o.x = f2bf(v.x); o.y = f2bf(v.y); o.z = f2bf(v.z); o.w = f2bf(v.w);
    ((ushort4*)dst)[i] = o;
}

// ---------------------------------------------------------------------------
// QKV GEMM: C = A @ B^T — 256x128 tile, BK=64, 8 waves (4x2, 64x64 each),
// MERGED 2-phase schedule: only 2 barriers + 1 lgkm + 1 counted vmcnt per
// K-tile (was 8/4/1 in the 4-phase form).
//   P1: ds_read ALL frags (16 b128) ; stage A(t+1)->buf^1 ; lgkmcnt(0)
//       [all waves' reads of BOTH buffers complete]; barrier ;
//       MFMA mt{0,1} x nt{0..3} (16)
//   P2: stage B(t+2)->cur buf (reads drained at P1 barrier) ;
//       MFMA mt{2,3} x nt{0..3} (16)
//   boundary: vmcnt(2) (A(t+1) retired, B(t+2) stays in flight) ; barrier
// Chunk-XOR swizzle (0 conflicts). RoPE fused into Q/K epilogue;
// z=2 writes V^T (B,H,64,S). Grid 768 = exactly 3/CU, XCD-aware decode.
// ---------------------------------------------------------------------------
__global__ __launch_bounds__(512, 1) void gemm_qkv_kernel(
    const ushort_t* __restrict__ A,
    const ushort_t* __restrict__ B0, const ushort_t* __restrict__ B1,
    const ushort_t* __restrict__ B2,
    void* __restrict__ C0, void* __restrict__ C1, void* __restrict__ C2,
    const float* __restrict__ cf, const float* __restrict__ sf,
    int M, int N, int K, int nz)
{
    __shared__ ushort_t As[2][16384];   // 256 rows x 64, chunk-swizzled
    __shared__ ushort_t Bs[2][8192];    // 128 rows x 64, chunk-swizzled

    const int lid = blockIdx.x;
    const int cpx = gridDim.x >> 3;
    const int wg  = (lid & 7) * cpx + (lid >> 3);
    const int x   = wg / (8 * nz);
    const int rr  = wg - x * (8 * nz);
    const int y   = rr & 7;
    const int z   = rr >> 3;

    const ushort_t* Bw = z == 0 ? B0 : z == 1 ? B1 : B2;
    void* Cv           = z == 0 ? C0 : z == 1 ? C1 : C2;

    const int tid  = threadIdx.x;
    const int wave = tid >> 6, lane = tid & 63;
    const int l15 = lane & 15, quad = lane >> 4;
    const int wr = wave >> 1, wc = wave & 1;   // 4 x 2 wave grid, 64x64 tiles
    const int mbase = x * 256;
    const int nbase = y * 128;
    const int NT = K >> 6;

    auto stageA = [&](int bt, int t) {     // full 256x64 tile: 4 ops/thread
#pragma unroll
        for (int L = 0; L < 4; ++L) {
            const int e8  = L * 512 + tid;
            const int row = e8 >> 3, c = e8 & 7;
            const ushort_t* src = A + (size_t)(mbase + row) * K + t * 64 + ((c ^ (row & 7)) << 3);
            __builtin_amdgcn_global_load_lds(
                (const __attribute__((address_space(1))) unsigned int*)src,
                (__attribute__((address_space(3))) unsigned int*)(&As[bt][e8 * 8]), 16, 0, 0);
        }
    };
    auto stageB = [&](int bt, int t) {     // full 128x64 tile: 2 ops/thread
#pragma unroll
        for (int L = 0; L < 2; ++L) {
            const int e8  = L * 512 + tid;
            const int row = e8 >> 3, c = e8 & 7;
            const ushort_t* src = Bw + (size_t)(nbase + row) * K + t * 64 + ((c ^ (row & 7)) << 3);
            __builtin_amdgcn_global_load_lds(
                (const __attribute__((address_space(1))) unsigned int*)src,
                (__attribute__((address_space(3))) unsigned int*)(&Bs[bt][e8 * 8]), 16, 0, 0);
        }
    };

    floatx4 acc[4][4] = {};

    // prologue: A0,B0 -> buf0; B1 -> buf1 (stays in flight past the wait)
    stageA(0, 0);
    stageB(0, 0);
    if (NT > 1) {
        stageB(1, 1);
        asm volatile("s_waitcnt vmcnt(2)" ::: "memory");
    } else {
        asm volatile("s_waitcnt vmcnt(0)" ::: "memory");
    }
    __builtin_amdgcn_s_barrier();

    for (int t = 0; t < NT; ++t) {
        const int bt = t & 1;
        bf16x8 af[2][4], bf[2][4];

        // ---- P1: read ALL frags ; stage A(t+1) ; lgkm ; barrier ; MFMA h0
#pragma unroll
        for (int kk = 0; kk < 2; ++kk) {
#pragma unroll
            for (int f = 0; f < 4; ++f) {
                const int row = wr * 64 + f * 16 + l15;
                af[kk][f] = *(const bf16x8*)&As[bt][row * 64 + ((((kk << 2) | quad)) ^ (l15 & 7)) * 8];
            }
#pragma unroll
            for (int g = 0; g < 4; ++g) {
                const int row = wc * 64 + g * 16 + l15;
                bf[kk][g] = *(const bf16x8*)&Bs[bt][row * 64 + ((((kk << 2) | quad)) ^ (l15 & 7)) * 8];
            }
        }
        if (t + 1 < NT) stageA(bt ^ 1, t + 1);
        asm volatile("s_waitcnt lgkmcnt(0)" ::: "memory");
        __builtin_amdgcn_s_barrier();
        __builtin_amdgcn_s_setprio(1);
#pragma unroll
        for (int kk = 0; kk < 2; ++kk)
#pragma unroll
            for (int mt = 0; mt < 2; ++mt)
#pragma unroll
                for (int nt = 0; nt < 4; ++nt)
                    acc[mt][nt] = __builtin_amdgcn_mfma_f32_16x16x32_bf16(
                        af[kk][mt], bf[kk][nt], acc[mt][nt], 0, 0, 0);
        __builtin_amdgcn_s_setprio(0);

        // ---- P2: stage B(t+2)->cur buf ; MFMA h1 ; counted vmcnt ; barrier
        if (t + 2 < NT) stageB(bt, t + 2);
        __builtin_amdgcn_s_setprio(1);
#pragma unroll
        for (int kk = 0; kk < 2; ++kk)
#pragma unroll
            for (int mt = 0; mt < 2; ++mt)
#pragma unroll
                for (int nt = 0; nt < 4; ++nt)
                    acc[2 + mt][nt] = __builtin_amdgcn_mfma_f32_16x16x32_bf16(
                        af[kk][2 + mt], bf[kk][nt], acc[2 + mt][nt], 0, 0, 0);
        __builtin_amdgcn_s_setprio(0);
        if (t + 2 < NT) { asm volatile("s_waitcnt vmcnt(2)" ::: "memory"); }
        else            { asm volatile("s_waitcnt vmcnt(0)" ::: "memory"); }
        __builtin_amdgcn_s_barrier();
    }

    const float qs = (z == 0) ? QSCALE : 1.0f;
#pragma unroll
    for (int mt = 0; mt < 4; ++mt) {
#pragma unroll
        for (int nt = 0; nt < 4; ++nt) {
            const int col = nbase + wc * 64 + nt * 16 + l15;
            const int m0  = mbase + wr * 64 + mt * 16 + quad * 4;
            if (z == 2) {
                const int b = m0 >> 11, s = m0 & 2047;
                const int hh = col >> 6, d = col & 63;
                uint2 pk;
                pk.x = (unsigned)f2bf(acc[mt][nt][0]) | ((unsigned)f2bf(acc[mt][nt][1]) << 16);
                pk.y = (unsigned)f2bf(acc[mt][nt][2]) | ((unsigned)f2bf(acc[mt][nt][3]) << 16);
                *(uint2*)&((ushort_t*)Cv)[((size_t)((b * NH_ + hh) * HD_ + d)) * S_ + s] = pk;
            } else {
                // fused RoPE: partner value lives in lane l15^1 (d^1)
                const int d = col & 63, j = d >> 1;
                const int hh = col >> 6;
                const float sgn = (l15 & 1) ? 1.0f : -1.0f;
#pragma unroll
                for (int r = 0; r < 4; ++r) {
                    const int m = m0 + r;
                    const int b = m >> 11, s = m & 2047;
                    const float v = acc[mt][nt][r];
                    const float p = __shfl_xor(v, 1, 64);
                    const float c  = cf[s * 32 + j] * qs;
                    const float sn = sf[s * 32 + j] * qs * sgn;
                    ((ushort_t*)Cv)[(((size_t)(b * NH_ + hh)) * S_ + s) * HD_ + d] =
                        f2bf(v * c + p * sn);
                }
            }
        }
    }
}

// ---------------------------------------------------------------------------
// Projection GEMM: C = A @ B^T — 128x128 tile, BK=64, 4 waves (2x2),
// 2 phases, 64 KB LDS -> 2 blocks/CU resident. f32 row-major output.
// Grid 1D = 64 * 8 = 512 blocks = 2/CU; XCD-aware decode. (unchanged)
// ---------------------------------------------------------------------------
__global__ __launch_bounds__(256, 2) void gemm_proj_kernel(
    const ushort_t* __restrict__ A, const ushort_t* __restrict__ Bw,
    float* __restrict__ Cv, int M, int N, int K)
{
    __shared__ ushort_t As[2][8192];    // 128 rows x 64, chunk-swizzled
    __shared__ ushort_t Bs[2][8192];

    const int lid = blockIdx.x;
    const int cpx = gridDim.x >> 3;
    const int wg  = (lid & 7) * cpx + (lid >> 3);
    const int x   = wg >> 3;
    const int y   = wg & 7;

    const int tid  = threadIdx.x;
    const int wave = tid >> 6, lane = tid & 63;
    const int l15 = lane & 15, quad = lane >> 4;
    const int wr = wave >> 1, wc = wave & 1;   // 2 x 2 wave grid
    const int mbase = x * 128;
    const int nbase = y * 128;
    const int NT = K >> 6;

    auto stageA = [&](int bt, int t) {
#pragma unroll
        for (int L = 0; L < 4; ++L) {
            const int e   = L * 256 + tid;
            const int row = e >> 3, c = e & 7;
            const ushort_t* src = A + (size_t)(mbase + row) * K + t * 64 + ((c ^ (row & 7)) << 3);
            __builtin_amdgcn_global_load_lds(
                (const __attribute__((address_space(1))) unsigned int*)src,
                (__attribute__((address_space(3))) unsigned int*)(&As[bt][e * 8]), 16, 0, 0);
        }
    };
    auto stageB = [&](int bt, int t) {
#pragma unroll
        for (int L = 0; L < 4; ++L) {
            const int e   = L * 256 + tid;
            const int row = e >> 3, c = e & 7;
            const ushort_t* src = Bw + (size_t)(nbase + row) * K + t * 64 + ((c ^ (row & 7)) << 3);
            __builtin_amdgcn_global_load_lds(
                (const __attribute__((address_space(1))) unsigned int*)src,
                (__attribute__((address_space(3))) unsigned int*)(&Bs[bt][e * 8]), 16, 0, 0);
        }
    };

    floatx4 acc[4][4] = {};

    stageA(0, 0);
    stageB(0, 0);
    if (NT > 1) {
        stageB(1, 1);
        asm volatile("s_waitcnt vmcnt(4)" ::: "memory");
    } else {
        asm volatile("s_waitcnt vmcnt(0)" ::: "memory");
    }
    __builtin_amdgcn_s_barrier();

    for (int t = 0; t < NT; ++t) {
        const int bt = t & 1;
        bf16x8 a0[2][2], a1[2][2], bf[2][4];

#pragma unroll
        for (int kk = 0; kk < 2; ++kk) {
#pragma unroll
            for (int f = 0; f < 2; ++f) {
                const int row = wr * 64 + f * 16 + l15;
                a0[kk][f] = *(const bf16x8*)&As[bt][row * 64 + ((((kk << 2) | quad)) ^ (l15 & 7)) * 8];
            }
#pragma unroll
            for (int g = 0; g < 4; ++g) {
                const int row = wc * 64 + g * 16 + l15;
                bf[kk][g] = *(const bf16x8*)&Bs[bt][row * 64 + ((((kk << 2) | quad)) ^ (l15 & 7)) * 8];
            }
        }
        if (t + 1 < NT) stageA(bt ^ 1, t + 1);
        asm volatile("s_waitcnt lgkmcnt(8)" ::: "memory");
        __builtin_amdgcn_s_barrier();
        asm volatile("s_waitcnt lgkmcnt(0)" ::: "memory");
        __builtin_amdgcn_s_setprio(1);
#pragma unroll
        for (int kk = 0; kk < 2; ++kk)
#pragma unroll
            for (int mt = 0; mt < 2; ++mt)
#pragma unroll
                for (int nt = 0; nt < 4; ++nt)
                    acc[mt][nt] = __builtin_amdgcn_mfma_f32_16x16x32_bf16(
                        a0[kk][mt], bf[kk][nt], acc[mt][nt], 0, 0, 0);
        __builtin_amdgcn_s_setprio(0);
        __builtin_amdgcn_s_barrier();

#pragma unroll
        for (int kk = 0; kk < 2; ++kk)
#pragma unroll
            for (int f = 0; f < 2; ++f) {
                const int row = wr * 64 + 32 + f * 16 + l15;
                a1[kk][f] = *(const bf16x8*)&As[bt][row * 64 + ((((kk << 2) | quad)) ^ (l15 & 7)) * 8];
            }
        if (t + 2 < NT) stageB(bt, t + 2);
        __builtin_amdgcn_s_barrier();
        asm volatile("s_waitcnt lgkmcnt(0)" ::: "memory");
        __builtin_amdgcn_s_setprio(1);
#pragma unroll
        for (int kk = 0; kk < 2; ++kk)
#pragma unroll
            for (int mt = 0; mt < 2; ++mt)
#pragma unroll
                for (int nt = 0; nt < 4; ++nt)
                    acc[2 + mt][nt] = __builtin_amdgcn_mfma_f32_16x16x32_bf16(
                        a1[kk][mt], bf[kk][nt], acc[2 + mt][nt], 0, 0, 0);
        __builtin_amdgcn_s_setprio(0);
        if (t + 2 < NT) { asm volatile("s_waitcnt vmcnt(4)" ::: "memory"); }
        else            { asm volatile("s_waitcnt vmcnt(0)" ::: "memory"); }
        __builtin_amdgcn_s_barrier();
    }

#pragma unroll
    for (int mt = 0; mt < 4; ++mt) {
#pragma unroll
        for (int nt = 0; nt < 4; ++nt) {
            const int col = nbase + wc * 64 + nt * 16 + l15;
            const int m0  = mbase + wr * 64 + mt * 16 + quad * 4;
#pragma unroll
            for (int r = 0; r < 4; ++r)
                Cv[(size_t)(m0 + r) * N + col] = acc[mt][nt][r];
        }
    }
}

// ---------------------------------------------------------------------------
// Causal flash attention v5 (unchanged from round 7): load-balance qt_tab,
// XCD/bh grouping, global_load_lds dbuf staging, in-register P via
// cvt_pk+permlane32_swap, defer-max THR=8.
// ---------------------------------------------------------------------------
__global__ __launch_bounds__(256, 4) void attn_kernel(
    const ushort_t* __restrict__ Qg, const ushort_t* __restrict__ Kg,
    const ushort_t* __restrict__ Vg, ushort_t* __restrict__ Og)
{
    __shared__ ushort_t Ks[2][64 * 64];    // [key][dim-chunk ^ (key&7)]
    __shared__ ushort_t Vt[2][64 * 64];    // [dim][key-chunk ^ (dim&7)]

    const int qt_tab[16] = {15,13,11,9, 0,2,4,6, 14,12,10,8, 1,3,5,7};

    const int id   = blockIdx.x;
    const int sg   = id >> 3;
    const int bh   = (id & 7) * 8 + (sg & 7);
    const int qtile = qt_tab[sg >> 3];
    const int tid  = threadIdx.x;
    const int wave = tid >> 6, lane = tid & 63;
    const int l31 = lane & 31, h = lane >> 5;

    const size_t bh_off = (size_t)bh * S_ * HD_;
    const int b_out = bh >> 4, h_out = bh & 15;

    const int e0 = tid, e1 = tid + 256;
    const int r0 = e0 >> 3, c0 = (e0 & 7) ^ (r0 & 7);
    const int r1 = e1 >> 3, c1 = (e1 & 7) ^ (r1 & 7);

    const int qbase = qtile * 128;
    const int nkt   = 2 * qtile + 2;
    const int qrow  = qbase + wave * 32 + l31;

    bf16x8 qf[4];
#pragma unroll
    for (int ks = 0; ks < 4; ++ks)
        qf[ks] = *(const bf16x8*)(Qg + bh_off + (size_t)qrow * HD_ + ks * 16 + h * 8);

    float m_run = -1e30f, l_run = 0.f;
    floatx16 o_acc[2] = {};

    {
        const ushort_t* ka = Kg + bh_off + (size_t)r0 * HD_ + c0 * 8;
        const ushort_t* kb = Kg + bh_off + (size_t)r1 * HD_ + c1 * 8;
        const ushort_t* va = Vg + bh_off + (size_t)r0 * S_ + c0 * 8;
        const ushort_t* vb = Vg + bh_off + (size_t)r1 * S_ + c1 * 8;
        __builtin_amdgcn_global_load_lds(
            (const __attribute__((address_space(1))) unsigned int*)ka,
            (__attribute__((address_space(3))) unsigned int*)(&Ks[0][e0 * 8]), 16, 0, 0);
        __builtin_amdgcn_global_load_lds(
            (const __attribute__((address_space(1))) unsigned int*)kb,
            (__attribute__((address_space(3))) unsigned int*)(&Ks[0][e1 * 8]), 16, 0, 0);
        __builtin_amdgcn_global_load_lds(
            (const __attribute__((address_space(1))) unsigned int*)va,
            (__attribute__((address_space(3))) unsigned int*)(&Vt[0][e0 * 8]), 16, 0, 0);
        __builtin_amdgcn_global_load_lds(
            (const __attribute__((address_space(1))) unsigned int*)vb,
            (__attribute__((address_space(3))) unsigned int*)(&Vt[0][e1 * 8]), 16, 0, 0);
    }
    asm volatile("s_waitcnt vmcnt(0)" ::: "memory");
    __syncthreads();

    for (int kt = 0; kt < nkt; ++kt) {
        const int kbase = kt * 64;
        const int cur = kt & 1;

        if (kt + 1 < nkt) {
            const int nb = kbase + 64;
            const ushort_t* ka = Kg + bh_off + (size_t)(nb + r0) * HD_ + c0 * 8;
            const ushort_t* kb = Kg + bh_off + (size_t)(nb + r1) * HD_ + c1 * 8;
            const ushort_t* va = Vg + bh_off + (size_t)r0 * S_ + nb + c0 * 8;
            const ushort_t* vb = Vg + bh_off + (size_t)r1 * S_ + nb + c1 * 8;
            __builtin_amdgcn_global_load_lds(
                (const __attribute__((address_space(1))) unsigned int*)ka,
                (__attribute__((address_space(3))) unsigned int*)(&Ks[cur ^ 1][e0 * 8]), 16, 0, 0);
            __builtin_amdgcn_global_load_lds(
                (const __attribute__((address_space(1))) unsigned int*)kb,
                (__attribute__((address_space(3))) unsigned int*)(&Ks[cur ^ 1][e1 * 8]), 16, 0, 0);
            __builtin_amdgcn_global_load_lds(
                (const __attribute__((address_space(1))) unsigned int*)va,
                (__attribute__((address_space(3))) unsigned int*)(&Vt[cur ^ 1][e0 * 8]), 16, 0, 0);
            __builtin_amdgcn_global_load_lds(
                (const __attribute__((address_space(1))) unsigned int*)vb,
                (__attribute__((address_space(3))) unsigned int*)(&Vt[cur ^ 1][e1 * 8]), 16, 0, 0);
        }

        if (kbase <= qbase + wave * 32 + 31) {
            floatx16 st[2] = {};
#pragma unroll
            for (int nt = 0; nt < 2; ++nt) {
                const int krow = nt * 32 + l31;
#pragma unroll
                for (int ks = 0; ks < 4; ++ks) {
                    bf16x8 kf = *(const bf16x8*)&Ks[cur][krow * 64 +
                                    (((ks * 2 + h) ^ (l31 & 7)) << 3)];
                    st[nt] = __builtin_amdgcn_mfma_f32_32x32x16_bf16(kf, qf[ks], st[nt], 0, 0, 0);
                }
            }
            if (kbase + 63 > qbase + wave * 32) {
#pragma unroll
                for (int nt = 0; nt < 2; ++nt) {
                    const int key0 = kbase + nt * 32 + 4 * h;
#pragma unroll
                    for (int c = 0; c < 4; ++c)
#pragma unroll
                        for (int r = 0; r < 4; ++r)
                            if (key0 + 8 * c + r > qrow) st[nt][c * 4 + r] = -1e9f;
                }
            }
            float mx = st[0][0];
#pragma unroll
            for (int nt = 0; nt < 2; ++nt)
#pragma unroll
                for (int i = 0; i < 16; ++i) mx = fmaxf(mx, st[nt][i]);
            mx = fmaxf(mx, __shfl_xor(mx, 32, 64));
            if (!__all(mx <= m_run + 8.0f)) {
                const float mnew = fmaxf(m_run, mx);
                const float alpha = __builtin_amdgcn_exp2f(m_run - mnew);
                m_run = mnew;
                l_run *= alpha;
#pragma unroll
                for (int dt = 0; dt < 2; ++dt)
#pragma unroll
                    for (int i = 0; i < 16; ++i) o_acc[dt][i] *= alpha;
            }
            float sum = 0.f;
#pragma unroll
            for (int nt = 0; nt < 2; ++nt)
#pragma unroll
                for (int i = 0; i < 16; ++i) {
                    const float p = __builtin_amdgcn_exp2f(st[nt][i] - m_run);
                    st[nt][i] = p; sum += p;
                }
            sum += __shfl_xor(sum, 32, 64);
            l_run += sum;

            bf16x8 pf[4];
#pragma unroll
            for (int ks = 0; ks < 4; ++ks) {
                const int nt = ks >> 1, base = (ks & 1) * 8;
                unsigned wrd[4];
#pragma unroll
                for (int d8 = 0; d8 < 2; ++d8) {
                    unsigned p = pack_bf16_trunc(st[nt][base + 2 * d8],
                                                 st[nt][base + 2 * d8 + 1]);
                    unsigned q = pack_bf16_trunc(st[nt][base + 4 + 2 * d8],
                                                 st[nt][base + 4 + 2 * d8 + 1]);
                    auto r = __builtin_amdgcn_permlane32_swap((int)p, (int)q, false, false);
                    wrd[d8]     = (unsigned)r[0];
                    wrd[2 + d8] = (unsigned)r[1];
                }
                union { unsigned u[4]; bf16x8 v; } cvt;
                cvt.u[0] = wrd[0]; cvt.u[1] = wrd[1];
                cvt.u[2] = wrd[2]; cvt.u[3] = wrd[3];
                pf[ks] = cvt.v;
            }

#pragma unroll
            for (int dt = 0; dt < 2; ++dt) {
                const int d = dt * 32 + l31;
#pragma unroll
                for (int ks = 0; ks < 4; ++ks) {
                    bf16x8 vf = *(const bf16x8*)&Vt[cur][d * 64 +
                                    (((ks * 2 + h) ^ (l31 & 7)) << 3)];
                    o_acc[dt] = __builtin_amdgcn_mfma_f32_32x32x16_bf16(vf, pf[ks], o_acc[dt], 0, 0, 0);
                }
            }
        }

        asm volatile("s_waitcnt vmcnt(0)" ::: "memory");
        __syncthreads();
    }

    const float inv = 1.0f / l_run;
    ushort_t* orow = Og + ((size_t)(b_out * S_ + qrow)) * DM_ + h_out * HD_;
#pragma unroll
    for (int dt = 0; dt < 2; ++dt)
#pragma unroll
        for (int c = 0; c < 4; ++c) {
            uint2 pk;
            pk.x = (unsigned)f2bf(o_acc[dt][c * 4 + 0] * inv) |
                   ((unsigned)f2bf(o_acc[dt][c * 4 + 1] * inv) << 16);
            pk.y = (unsigned)f2bf(o_acc[dt][c * 4 + 2] * inv) |
                   ((unsigned)f2bf(o_acc[dt][c * 4 + 3] * inv) << 16);
            *(uint2*)(orow + dt * 32 + 8 * c + 4 * h) = pk;
        }
}

// ---------------------------------------------------------------------------
extern "C" void kernel_launch(void* const* d_in, const int* in_sizes, int n_in,
                              void* d_out, int out_size, void* d_ws, size_t ws_size,
                              hipStream_t stream)
{
    const float* x  = (const float*)d_in[0];
    const float* cf = (const float*)d_in[1];
    const float* sf = (const float*)d_in[2];
    // d_in[3] = causal_mask: computed analytically, never read
    const float* wq = (const float*)d_in[4];
    const float* wk = (const float*)d_in[5];
    const float* wv = (const float*)d_in[6];
    const float* wo = (const float*)d_in[7];
    float* out = (float*)d_out;

    const size_t NELEM = (size_t)B_ * S_ * DM_;   // 8388608
    const size_t WELEM = (size_t)DM_ * DM_;       // 1048576
    ushort_t* xb  = (ushort_t*)d_ws;
    ushort_t* qb  = xb + NELEM;
    ushort_t* kb  = qb + NELEM;
    ushort_t* vb  = kb + NELEM;                   // V^T (B,H,64,S)
    ushort_t* ao  = vb + NELEM;
    ushort_t* wqb = ao + NELEM;
    ushort_t* wkb = wqb + WELEM;
    ushort_t* wvb = wkb + WELEM;
    ushort_t* wob = wvb + WELEM;

    cvt_all_kernel<<<dim3(8192 + 4 * 1024), 256, 0, stream>>>(
        x, wq, wk, wv, wo, xb, wqb, wkb, wvb, wob);

    const int M = B_ * S_;
    // QKV (+fused RoPE): 32 * 8 * 3 = 768 blocks = exactly 3/CU, 512 thr
    gemm_qkv_kernel<<<dim3(32 * 8 * 3), 512, 0, stream>>>(
        xb, wqb, wkb, wvb, qb, kb, vb, cf, sf, M, DM_, DM_, 3);
    attn_kernel<<<dim3(1024), 256, 0, stream>>>(qb, kb, vb, ao);
    // proj: 64 * 8 = 512 blocks = 2/CU resident
    gemm_proj_kernel<<<dim3(64 * 8), 256, 0, stream>>>(
        ao, wob, out, M, DM_, DM_);
}